// Round 1
// baseline (160.331 us; speedup 1.0000x reference)
//
#include <hip/hip_runtime.h>
#include <hip/hip_bf16.h>

// Fused windowed attention + FC projection for MI355X (gfx950).
// One block per (batch, window): 256 threads = 4 waves, 2 heads per wave.
// All matmuls via v_mfma_f32_16x16x32_bf16 (bf16 in, fp32 acc).

typedef __attribute__((ext_vector_type(8))) short bf8;   // 8 bf16 = 4 VGPRs
typedef __attribute__((ext_vector_type(4))) float f4;    // MFMA C/D

#define SCALE 0.17677669529663687f                 // 1/sqrt(32)
#define CC (SCALE * 1.4426950408889634f)           // SCALE * log2(e)

static __device__ __forceinline__ unsigned short f2bf(float x) {
  // round-to-nearest-even f32 -> bf16 (no NaN handling; inputs are finite)
  unsigned u = __float_as_uint(x);
  u += 0x7FFFu + ((u >> 16) & 1u);
  return (unsigned short)(u >> 16);
}

static __device__ __forceinline__ bf8 load_bf8_f32(const float* __restrict__ p) {
  float4 a = *(const float4*)p;
  float4 b = *(const float4*)(p + 4);
  bf8 r;
  r[0] = (short)f2bf(a.x); r[1] = (short)f2bf(a.y);
  r[2] = (short)f2bf(a.z); r[3] = (short)f2bf(a.w);
  r[4] = (short)f2bf(b.x); r[5] = (short)f2bf(b.y);
  r[6] = (short)f2bf(b.z); r[7] = (short)f2bf(b.w);
  return r;
}

// LDS budget (ushort units): attention phase: per-wave P [64][72] (4608 us)
// at w*4608, per-wave V^T [32][72] (2304 us) at 18432 + w*2304.
// FC phase (after barrier): inter [64][264] (16896 us) unioned at offset 0.
// Total 27648 us = 55296 B -> 2 blocks/CU.
__global__ __launch_bounds__(256, 2) void win_attn_fc(
    const float* __restrict__ q, const float* __restrict__ k,
    const float* __restrict__ v, const float* __restrict__ W,
    float* __restrict__ out) {
  __shared__ unsigned short smem[27648];
  const int tid  = threadIdx.x;
  const int wave = tid >> 6;
  const int lane = tid & 63;
  const int g    = lane >> 4;   // 0..3  (k-chunk group / output row group)
  const int c16  = lane & 15;   // 0..15 (within-tile row/col)

  const int blk = blockIdx.x;
  const int b   = blk >> 8;          // 256 windows per batch
  const int wy  = (blk >> 4) & 15;
  const int wx  = blk & 15;
  // token row for window-local index m (0..63): r=m>>3, c=m&7
  const long tokbase = (long)b * 16384 + (long)(wy * 8) * 128 + wx * 8;

  unsigned short* Pl = smem + wave * 4608;          // [64 q][72] bf16
  unsigned short* VT = smem + 18432 + wave * 2304;  // [32 d][72] bf16 (V^T)

  f4 O[2][4][2];  // [head][ti][dt] attention out, rows 16ti+4g+r, cols c16+16dt

  #pragma unroll
  for (int hh = 0; hh < 2; ++hh) {
    const int h = wave * 2 + hh;

    // ---- stage V^T: lane owns kv-row kk=lane, writes 32 channels transposed ----
    {
      const long vr = tokbase + (lane >> 3) * 128 + (lane & 7);
      const float* vp = v + vr * 256 + h * 32;
      #pragma unroll
      for (int j = 0; j < 8; ++j) {
        float4 vv = *(const float4*)(vp + 4 * j);
        VT[(4*j+0)*72 + lane] = f2bf(vv.x);
        VT[(4*j+1)*72 + lane] = f2bf(vv.y);
        VT[(4*j+2)*72 + lane] = f2bf(vv.z);
        VT[(4*j+3)*72 + lane] = f2bf(vv.w);
      }
    }

    // ---- Q,K fragments direct from global: A/B layout row=l&15, k=8*(l>>4)+j ----
    bf8 qf[4], kf[4];
    #pragma unroll
    for (int t = 0; t < 4; ++t) {
      const int m = 16 * t + c16;
      const long r = tokbase + (m >> 3) * 128 + (m & 7);
      qf[t] = load_bf8_f32(q + r * 256 + h * 32 + g * 8);
      kf[t] = load_bf8_f32(k + r * 256 + h * 32 + g * 8);
    }

    // ---- S = Q K^T : 4x4 tiles of 16x16, K=32 in one MFMA each ----
    f4 S[4][4];
    #pragma unroll
    for (int ti = 0; ti < 4; ++ti) {
      #pragma unroll
      for (int tj = 0; tj < 4; ++tj) {
        f4 z = {0.f, 0.f, 0.f, 0.f};
        S[ti][tj] = __builtin_amdgcn_mfma_f32_16x16x32_bf16(qf[ti], kf[tj], z, 0, 0, 0);
      }
    }

    // ---- row softmax: lane owns rows 16ti+4g+r; cols spread over l&15 x tj ----
    float rec[4][4];
    #pragma unroll
    for (int ti = 0; ti < 4; ++ti) {
      #pragma unroll
      for (int r = 0; r < 4; ++r) {
        float m = -1e30f;
        #pragma unroll
        for (int tj = 0; tj < 4; ++tj) m = fmaxf(m, S[ti][tj][r]);
        m = fmaxf(m, __shfl_xor(m, 1));
        m = fmaxf(m, __shfl_xor(m, 2));
        m = fmaxf(m, __shfl_xor(m, 4));
        m = fmaxf(m, __shfl_xor(m, 8));
        const float mm = m * CC;
        float ds = 0.f;
        #pragma unroll
        for (int tj = 0; tj < 4; ++tj) {
          float p = exp2f(S[ti][tj][r] * CC - mm);
          ds += p;
          Pl[(16*ti + 4*g + r) * 72 + 16*tj + c16] = f2bf(p);
        }
        ds += __shfl_xor(ds, 1);
        ds += __shfl_xor(ds, 2);
        ds += __shfl_xor(ds, 4);
        ds += __shfl_xor(ds, 8);
        rec[ti][r] = 1.0f / ds;
      }
    }

    // ---- O = P V : A=P from LDS (contiguous b128), B=V from VT (contiguous) ----
    #pragma unroll
    for (int ti = 0; ti < 4; ++ti) {
      #pragma unroll
      for (int dt = 0; dt < 2; ++dt) {
        f4 acc = {0.f, 0.f, 0.f, 0.f};
        #pragma unroll
        for (int kt = 0; kt < 2; ++kt) {
          bf8 pf = *(const bf8*)(Pl + (16*ti + c16) * 72 + 32*kt + 8*g);
          bf8 vf = *(const bf8*)(VT + (16*dt + c16) * 72 + 32*kt + 8*g);
          acc = __builtin_amdgcn_mfma_f32_16x16x32_bf16(pf, vf, acc, 0, 0, 0);
        }
        #pragma unroll
        for (int r = 0; r < 4; ++r) acc[r] *= rec[ti][r];
        O[hh][ti][dt] = acc;
      }
    }
  }

  // ---- assemble inter[64 tokens][256 ch] bf16 (pad->264) over dead P/VT ----
  __syncthreads();
  unsigned short* inter = smem;
  #pragma unroll
  for (int hh = 0; hh < 2; ++hh) {
    const int h = wave * 2 + hh;
    #pragma unroll
    for (int ti = 0; ti < 4; ++ti)
      #pragma unroll
      for (int dt = 0; dt < 2; ++dt)
        #pragma unroll
        for (int r = 0; r < 4; ++r)
          inter[(16*ti + 4*g + r) * 264 + h * 32 + 16*dt + c16] = f2bf(O[hh][ti][dt][r]);
  }
  __syncthreads();

  // ---- FC: out[0:64][64w:64w+64] = inter[64][256] @ W^T; W read fp32 (L2-hot) ----
  f4 acc[4][4];
  #pragma unroll
  for (int mt = 0; mt < 4; ++mt) {
    #pragma unroll
    for (int nt = 0; nt < 4; ++nt) {
      f4 z = {0.f, 0.f, 0.f, 0.f};
      acc[mt][nt] = z;
    }
  }
  #pragma unroll
  for (int ks = 0; ks < 8; ++ks) {
    bf8 af[4], wf[4];
    #pragma unroll
    for (int mt = 0; mt < 4; ++mt)
      af[mt] = *(const bf8*)(inter + (16*mt + c16) * 264 + 32*ks + 8*g);
    #pragma unroll
    for (int nt = 0; nt < 4; ++nt)
      wf[nt] = load_bf8_f32(W + (long)(64*wave + 16*nt + c16) * 256 + 32*ks + 8*g);
    #pragma unroll
    for (int mt = 0; mt < 4; ++mt)
      #pragma unroll
      for (int nt = 0; nt < 4; ++nt)
        acc[mt][nt] = __builtin_amdgcn_mfma_f32_16x16x32_bf16(af[mt], wf[nt], acc[mt][nt], 0, 0, 0);
  }

  // ---- epilogue: scatter back through window merge, fp32 stores ----
  #pragma unroll
  for (int mt = 0; mt < 4; ++mt) {
    #pragma unroll
    for (int r = 0; r < 4; ++r) {
      const int m = 16*mt + 4*g + r;
      const long row = tokbase + (m >> 3) * 128 + (m & 7);
      float* op = out + row * 256 + 64*wave + c16;
      #pragma unroll
      for (int nt = 0; nt < 4; ++nt)
        op[16*nt] = acc[mt][nt][r];
    }
  }
}

extern "C" void kernel_launch(void* const* d_in, const int* in_sizes, int n_in,
                              void* d_out, int out_size, void* d_ws, size_t ws_size,
                              hipStream_t stream) {
  const float* q = (const float*)d_in[0];
  const float* k = (const float*)d_in[1];
  const float* v = (const float*)d_in[2];
  const float* W = (const float*)d_in[3];
  float* out = (float*)d_out;
  const int B = in_sizes[0] / (16384 * 256);
  win_attn_fc<<<dim3(B * 256), dim3(256), 0, stream>>>(q, k, v, W, out);
}

// Round 3
// 134.261 us; speedup vs baseline: 1.1942x; 1.1942x over previous
//
#include <hip/hip_runtime.h>
#include <hip/hip_bf16.h>

// Fused windowed attention + FC projection for MI355X (gfx950).
// One block per (batch, window): 256 threads = 4 waves, 2 heads per wave.
// Attention uses swapped-operand MFMA (S^T = K*Q^T) so softmax rows are
// lane-local columns and P^T fragments are built by shuffles -- no P LDS.
// LDS: per-wave V^T [32][72] bf16 (9216 B total), aliased under
// inter [64][264] bf16 (33792 B) -> 4 blocks/CU, 16 waves/CU.

typedef __attribute__((ext_vector_type(8))) short bf8;   // 8 bf16 = 4 VGPRs
typedef __attribute__((ext_vector_type(4))) float f4;    // MFMA C/D

#define SCALE 0.17677669529663687f                 // 1/sqrt(32)
#define CC (SCALE * 1.4426950408889634f)           // SCALE * log2(e)

static __device__ __forceinline__ unsigned short f2bf(float x) {
  unsigned u = __float_as_uint(x);
  u += 0x7FFFu + ((u >> 16) & 1u);
  return (unsigned short)(u >> 16);
}
static __device__ __forceinline__ unsigned pk2(float a, float b) {
  return (unsigned)f2bf(a) | ((unsigned)f2bf(b) << 16);
}
union FragU { unsigned u[4]; bf8 v; };

static __device__ __forceinline__ bf8 load_bf8_f32(const float* __restrict__ p) {
  float4 a = *(const float4*)p;
  float4 b = *(const float4*)(p + 4);
  FragU f;
  f.u[0] = pk2(a.x, a.y);
  f.u[1] = pk2(a.z, a.w);
  f.u[2] = pk2(b.x, b.y);
  f.u[3] = pk2(b.z, b.w);
  return f.v;
}

__global__ void wcvt(const float* __restrict__ W, unsigned short* __restrict__ Wb) {
  const int i = (blockIdx.x * 256 + threadIdx.x) * 4;
  float4 w = *(const float4*)(W + i);
  ushort4 o;
  o.x = f2bf(w.x); o.y = f2bf(w.y); o.z = f2bf(w.z); o.w = f2bf(w.w);
  *(ushort4*)(Wb + i) = o;
}

template <bool WB16>
__global__ __launch_bounds__(256, 4) void win_attn_fc(
    const float* __restrict__ q, const float* __restrict__ k,
    const float* __restrict__ v, const void* __restrict__ Wp,
    float* __restrict__ out) {
  __shared__ unsigned short smem[16896];   // 33792 B: inter[64][264]; VT aliased
  const int tid  = threadIdx.x;
  const int wave = tid >> 6;
  const int lane = tid & 63;
  const int g    = lane >> 4;   // 0..3
  const int c16  = lane & 15;   // 0..15

  const int blk = blockIdx.x;
  const int b   = blk >> 8;          // 256 windows per batch
  const int wy  = (blk >> 4) & 15;
  const int wx  = blk & 15;
  const long tokbase = (long)b * 16384 + (long)(wy * 8) * 128 + wx * 8;

  unsigned short* VT = smem + wave * 2304;  // [32 d][72 tok] bf16, per wave

  // packed bf16 attention outputs: [head][dt][tiq][word], word w = rows 2w,2w+1
  unsigned opk[2][2][4][2];

  const int  srcA = c16 + ((g & 1) << 5);   // shuffle source lane (group 2*(g&1))
  const bool hi   = (g >> 1) != 0;          // selects tj = 2kt+1 source register

  #pragma unroll
  for (int hh = 0; hh < 2; ++hh) {
    const int h = wave * 2 + hh;

    // ---- stage V^T: lane owns token lane, writes its 32 channels transposed ----
    {
      const long vr = tokbase + (lane >> 3) * 128 + (lane & 7);
      const float* vp = v + vr * 256 + h * 32;
      #pragma unroll
      for (int j = 0; j < 8; ++j) {
        float4 vv = *(const float4*)(vp + 4 * j);
        VT[(4*j+0)*72 + lane] = f2bf(vv.x);
        VT[(4*j+1)*72 + lane] = f2bf(vv.y);
        VT[(4*j+2)*72 + lane] = f2bf(vv.z);
        VT[(4*j+3)*72 + lane] = f2bf(vv.w);
      }
    }

    // ---- Q,K fragments direct from global (A/B layout: row=l&15, k=8*(l>>4)+j) ----
    bf8 qf[4], kf[4];
    #pragma unroll
    for (int t = 0; t < 4; ++t) {
      const int m = 16 * t + c16;
      const long r = tokbase + (m >> 3) * 128 + (m & 7);
      qf[t] = load_bf8_f32(q + r * 256 + h * 32 + g * 8);
      kf[t] = load_bf8_f32(k + r * 256 + h * 32 + g * 8);
    }

    #pragma unroll
    for (int ti = 0; ti < 4; ++ti) {
      // ---- S^T tiles for this q-tile: rows k = 16tj+4g+r, col q = 16ti+c16 ----
      f4 st[4];
      #pragma unroll
      for (int tj = 0; tj < 4; ++tj) {
        f4 z = {0.f, 0.f, 0.f, 0.f};
        st[tj] = __builtin_amdgcn_mfma_f32_16x16x32_bf16(kf[tj], qf[ti], z, 0, 0, 0);
      }
      // ---- softmax over k for q=16ti+c16 (16 local vals + 2 shfl) ----
      float mx = st[0][0];
      #pragma unroll
      for (int tj = 0; tj < 4; ++tj)
        #pragma unroll
        for (int r = 0; r < 4; ++r) mx = fmaxf(mx, st[tj][r]);
      mx = fmaxf(mx, __shfl_xor(mx, 16));
      mx = fmaxf(mx, __shfl_xor(mx, 32));
      const float mm = mx * CC;
      float pe[4][4];
      float ds = 0.f;
      #pragma unroll
      for (int tj = 0; tj < 4; ++tj)
        #pragma unroll
        for (int r = 0; r < 4; ++r) {
          float p = exp2f(st[tj][r] * CC - mm);
          pe[tj][r] = p;
          ds += p;
        }
      ds += __shfl_xor(ds, 16);
      ds += __shfl_xor(ds, 32);
      const float rc = 1.0f / ds;
      // pack normalized P as bf16 pairs: PW[tj][w] = rows 4g+2w, 4g+2w+1
      unsigned PW[4][2];
      #pragma unroll
      for (int tj = 0; tj < 4; ++tj) {
        PW[tj][0] = pk2(pe[tj][0] * rc, pe[tj][1] * rc);
        PW[tj][1] = pk2(pe[tj][2] * rc, pe[tj][3] * rc);
      }
      // ---- O^T tiles (dt, ti) = sum_kt V^T_frag x P^T_frag ----
      f4 acc0 = {0.f, 0.f, 0.f, 0.f};
      f4 acc1 = {0.f, 0.f, 0.f, 0.f};
      #pragma unroll
      for (int kt = 0; kt < 2; ++kt) {
        // build P^T B-fragment: j=0..7 -> k = 32kt+8g+j, q=c16 (shuffle in column)
        unsigned a0 = __shfl(PW[2*kt  ][0], srcA);
        unsigned a1 = __shfl(PW[2*kt  ][1], srcA);
        unsigned a2 = __shfl(PW[2*kt  ][0], srcA + 16);
        unsigned a3 = __shfl(PW[2*kt  ][1], srcA + 16);
        unsigned b0 = __shfl(PW[2*kt+1][0], srcA);
        unsigned b1 = __shfl(PW[2*kt+1][1], srcA);
        unsigned b2 = __shfl(PW[2*kt+1][0], srcA + 16);
        unsigned b3 = __shfl(PW[2*kt+1][1], srcA + 16);
        FragU pf;
        pf.u[0] = hi ? b0 : a0;
        pf.u[1] = hi ? b1 : a1;
        pf.u[2] = hi ? b2 : a2;
        pf.u[3] = hi ? b3 : a3;
        bf8 vf0 = *(const bf8*)(VT + (c16     ) * 72 + 32*kt + 8*g);
        bf8 vf1 = *(const bf8*)(VT + (16 + c16) * 72 + 32*kt + 8*g);
        acc0 = __builtin_amdgcn_mfma_f32_16x16x32_bf16(vf0, pf.v, acc0, 0, 0, 0);
        acc1 = __builtin_amdgcn_mfma_f32_16x16x32_bf16(vf1, pf.v, acc1, 0, 0, 0);
      }
      // pack O^T to bf16: channel = 16dt+4g+2w(+1), token q = 16ti+c16
      opk[hh][0][ti][0] = pk2(acc0[0], acc0[1]);
      opk[hh][0][ti][1] = pk2(acc0[2], acc0[3]);
      opk[hh][1][ti][0] = pk2(acc1[0], acc1[1]);
      opk[hh][1][ti][1] = pk2(acc1[2], acc1[3]);
    }
  }

  // ---- assemble inter[64 tok][264 ch] bf16 (aliases VT -> barrier first) ----
  __syncthreads();
  unsigned short* inter = smem;
  #pragma unroll
  for (int hh = 0; hh < 2; ++hh)
    #pragma unroll
    for (int dt = 0; dt < 2; ++dt)
      #pragma unroll
      for (int ti = 0; ti < 4; ++ti) {
        const int addr = (16*ti + c16) * 264 + (wave*2 + hh) * 32 + 16*dt + 4*g;
        uint2 wv;
        wv.x = opk[hh][dt][ti][0];
        wv.y = opk[hh][dt][ti][1];
        *(uint2*)(inter + addr) = wv;   // 8B-aligned: addr % 4 == 0
      }
  __syncthreads();

  // ---- FC: out[tok][64w..64w+63] = inter[64][256] @ W^T ----
  f4 acc[4][4];
  #pragma unroll
  for (int mt = 0; mt < 4; ++mt)
    #pragma unroll
    for (int nt = 0; nt < 4; ++nt) {
      f4 z = {0.f, 0.f, 0.f, 0.f};
      acc[mt][nt] = z;
    }
  const float* Wf          = (const float*)Wp;
  const unsigned short* Wb = (const unsigned short*)Wp;
  #pragma unroll
  for (int ks = 0; ks < 8; ++ks) {
    bf8 af[4], wf[4];
    #pragma unroll
    for (int mt = 0; mt < 4; ++mt)
      af[mt] = *(const bf8*)(inter + (16*mt + c16) * 264 + 32*ks + 8*g);
    #pragma unroll
    for (int nt = 0; nt < 4; ++nt) {
      const long widx = (long)(64*wave + 16*nt + c16) * 256 + 32*ks + 8*g;
      if (WB16) wf[nt] = *(const bf8*)(Wb + widx);
      else      wf[nt] = load_bf8_f32(Wf + widx);
    }
    #pragma unroll
    for (int mt = 0; mt < 4; ++mt)
      #pragma unroll
      for (int nt = 0; nt < 4; ++nt)
        acc[mt][nt] = __builtin_amdgcn_mfma_f32_16x16x32_bf16(af[mt], wf[nt], acc[mt][nt], 0, 0, 0);
  }

  // ---- epilogue: scatter back through window merge, fp32 stores ----
  #pragma unroll
  for (int mt = 0; mt < 4; ++mt) {
    #pragma unroll
    for (int r = 0; r < 4; ++r) {
      const int m = 16*mt + 4*g + r;
      const long row = tokbase + (m >> 3) * 128 + (m & 7);
      float* op = out + row * 256 + 64*wave + c16;
      #pragma unroll
      for (int nt = 0; nt < 4; ++nt)
        op[16*nt] = acc[mt][nt][r];
    }
  }
}

extern "C" void kernel_launch(void* const* d_in, const int* in_sizes, int n_in,
                              void* d_out, int out_size, void* d_ws, size_t ws_size,
                              hipStream_t stream) {
  const float* q = (const float*)d_in[0];
  const float* k = (const float*)d_in[1];
  const float* v = (const float*)d_in[2];
  const float* W = (const float*)d_in[3];
  float* out = (float*)d_out;
  const int B = in_sizes[0] / (16384 * 256);
  const size_t wbytes = 65536 * sizeof(unsigned short);
  if (ws_size >= wbytes) {
    wcvt<<<dim3(64), dim3(256), 0, stream>>>(W, (unsigned short*)d_ws);
    win_attn_fc<true><<<dim3(B * 256), dim3(256), 0, stream>>>(q, k, v, d_ws, out);
  } else {
    win_attn_fc<false><<<dim3(B * 256), dim3(256), 0, stream>>>(q, k, v, W, out);
  }
}